// Round 7
// baseline (382.840 us; speedup 1.0000x reference)
//
#include <hip/hip_runtime.h>
#include <math.h>

// Problem constants (S=2048, B=16, H=1024)
#define S_LEN 2048
#define B_SZ  16
#define H_SZ  1024
#define M_SZ  32768

typedef __attribute__((ext_vector_type(8))) _Float16 half8;  // 4 VGPR
typedef __attribute__((ext_vector_type(4))) float f32x4;     // MFMA C/D

__device__ __forceinline__ unsigned pack2h(float a, float b) {
    _Float16 ha = (_Float16)a, hb = (_Float16)b;
    unsigned short ua = __builtin_bit_cast(unsigned short, ha);
    unsigned short ub = __builtin_bit_cast(unsigned short, hb);
    return (unsigned)ua | ((unsigned)ub << 16);
}

// Conflict-free LDS tile layout for [128 rows][32 f16] (64 B logical rows):
// row-pairs share a 128 B line; 16B-slot index XOR'd by line&7 so every
// b128 frag read covers each 128 B line exactly once (minimum aliasing).
__device__ __forceinline__ int phys_off(int r, int sl) {
    return ((r >> 1) << 7) + ((((r & 1) << 2 | sl) ^ ((r >> 1) & 7)) << 4);
}

// async global->LDS, 16 B per lane. dest must be wave-uniform (HW adds lane*16).
__device__ __forceinline__ void dma16(const void* g, void* l) {
    __builtin_amdgcn_global_load_lds(
        (const __attribute__((address_space(1))) unsigned int*)g,
        (__attribute__((address_space(3))) unsigned int*)l, 16, 0, 0);
}

// ---------------------------------------------------------------------------
// K1: hp[b][h] = dot(hidden[b], W1[h]) + b_att[h]  (R2-proven structure:
// one wave per (b,h), 4096 blocks -> massively parallel, latency-tolerant)
// ---------------------------------------------------------------------------
__global__ void k_hidden_part(const float* __restrict__ hidden,
                              const float* __restrict__ W,
                              const float* __restrict__ b_att,
                              float* __restrict__ hp) {
    int gid  = blockIdx.x * blockDim.x + threadIdx.x;
    int wave = gid >> 6;
    int lane = threadIdx.x & 63;
    int b = wave >> 10;
    int h = wave & 1023;
    const float* x = hidden + b * H_SZ;
    const float* w = W + (size_t)h * (2 * H_SZ);
    float acc = 0.f;
    #pragma unroll
    for (int k = 0; k < H_SZ; k += 64) acc += x[k + lane] * w[k + lane];
    #pragma unroll
    for (int off = 32; off; off >>= 1) acc += __shfl_down(acc, off, 64);
    if (lane == 0) hp[b * H_SZ + h] = acc + b_att[h];
}

// ---------------------------------------------------------------------------
// K0: W2 -> fp16, pre-swizzled into per-(n-panel,kt) 8 KB tiles that are the
// exact LDS image (so global_load_lds copies linearly, reads stay swizzled).
// ---------------------------------------------------------------------------
__global__ void k_convw(const float* __restrict__ W,
                        unsigned short* __restrict__ Wsw) {
    int t = blockIdx.x * 256 + threadIdx.x;       // 131072 threads
    int sl = t & 3, r = (t >> 2) & 127, kt = (t >> 9) & 31, nt = t >> 14;
    const float* src = W + (size_t)(nt * 128 + r) * 2048 + 1024 + kt * 32 + sl * 8;
    float4 f0 = *(const float4*)src;
    float4 f1 = *(const float4*)(src + 4);
    uint4 u;
    u.x = pack2h(f0.x, f0.y); u.y = pack2h(f0.z, f0.w);
    u.z = pack2h(f1.x, f1.y); u.w = pack2h(f1.z, f1.w);
    *(uint4*)((char*)Wsw + (size_t)(nt * 32 + kt) * 8192 + phys_off(r, sl)) = u;
}

// ===========================================================================
// K2: fp16 MFMA GEMM + tanh + v-dot.
// Tile 128x128, BK=32, 256 thr = 4 waves (2x2), per-wave 64x64.
// A: reg-staged (f32->f16 convert), issue-early/write-late.
// B: global_load_lds DMA from pre-swizzled Wsw (no VGPR round trip).
// LDS 2 x 16 KB; conflict-free phys layout on both operands.
// ===========================================================================
#define SA    0
#define SB    8192
#define SBUF  16384

__global__ __launch_bounds__(256, 3)
void k_score_dma(const float* __restrict__ X,            // [32768][1024] f32
                 const unsigned short* __restrict__ Wsw, // swizzled f16 tiles
                 const float* __restrict__ hp,           // [16][1024]
                 const float* __restrict__ v,            // [1024]
                 float* __restrict__ score_part) {       // [8][32768]
    __shared__ char lds[2 * SBUF];

    const int t = threadIdx.x;
    // XCD-chunked bijective swizzle (2048 wgs, %8==0), m-panel-major per XCD
    int wg = (blockIdx.x & 7) * 256 + (blockIdx.x >> 3);
    const int m0 = (wg >> 3) * 128;
    const int nt = wg & 7;
    const int n0 = nt * 128;

    const int lane = t & 63, wid = t >> 6;
    const int wm = wid >> 1, wn = wid & 1;       // 2 x 2 waves
    const int lr = lane & 15, lq = lane >> 4;

    // A staging: thread covers row srow, k-half shalf (16 f32 = 4 float4)
    const int srow = t >> 1, shalf = t & 1;
    const float* Xp = X + (size_t)(m0 + srow) * 1024 + shalf * 16;
    const int aOff0 = phys_off(srow, shalf * 2 + 0);
    const int aOff1 = phys_off(srow, shalf * 2 + 1);

    // B DMA source: wave wid loads 2 x 1KB chunks per kt (per-lane addr)
    const unsigned short* Bp = Wsw + (size_t)(nt * 32) * 4096 + wid * 1024 + lane * 8;

    // fragment read offsets (swizzled)
    int aro[4], bro[4];
    #pragma unroll
    for (int i = 0; i < 4; ++i) {
        aro[i] = phys_off(wm * 64 + i * 16 + lr, lq);
        bro[i] = phys_off(wn * 64 + i * 16 + lr, lq);
    }

    f32x4 acc[4][4];
    #pragma unroll
    for (int i = 0; i < 4; ++i)
        #pragma unroll
        for (int j = 0; j < 4; ++j) acc[i][j] = (f32x4)0.f;

    float4 ax[4];

#define LOADA(kt)                                                              \
    {                                                                          \
        const float* p = Xp + (kt) * 32;                                       \
        ax[0] = *(const float4*)(p);                                           \
        ax[1] = *(const float4*)(p + 4);                                       \
        ax[2] = *(const float4*)(p + 8);                                       \
        ax[3] = *(const float4*)(p + 12);                                      \
    }

#define DMAB(bufbase, kt)                                                      \
    {                                                                          \
        const unsigned short* s0 = Bp + (size_t)(kt) * 4096;                   \
        dma16(s0,       (bufbase) + SB + wid * 2048);                          \
        dma16(s0 + 512, (bufbase) + SB + wid * 2048 + 1024);                   \
    }

#define STAGEA(bufbase)                                                        \
    {                                                                          \
        uint4 p0, p1;                                                          \
        p0.x = pack2h(ax[0].x, ax[0].y); p0.y = pack2h(ax[0].z, ax[0].w);      \
        p0.z = pack2h(ax[1].x, ax[1].y); p0.w = pack2h(ax[1].z, ax[1].w);      \
        p1.x = pack2h(ax[2].x, ax[2].y); p1.y = pack2h(ax[2].z, ax[2].w);      \
        p1.z = pack2h(ax[3].x, ax[3].y); p1.w = pack2h(ax[3].z, ax[3].w);      \
        *(uint4*)((bufbase) + SA + aOff0) = p0;                                \
        *(uint4*)((bufbase) + SA + aOff1) = p1;                                \
    }

    LOADA(0);
    DMAB(lds, 0);
    STAGEA(lds);
    __syncthreads();   // drains A writes (lgkm) + B DMA (vmcnt)

    for (int kt = 0; kt < 32; ++kt) {
        char* cur = lds + (kt & 1) * SBUF;
        char* nxt = lds + ((kt & 1) ^ 1) * SBUF;
        if (kt < 31) {
            LOADA(kt + 1);      // oldest vmcnt entries: ax
            DMAB(nxt, kt + 1);  // younger: B DMA stays in flight at STAGEA wait
        }

        half8 ah[4], bh[4];
        #pragma unroll
        for (int i = 0; i < 4; ++i) ah[i] = *(const half8*)(cur + SA + aro[i]);
        #pragma unroll
        for (int j = 0; j < 4; ++j) bh[j] = *(const half8*)(cur + SB + bro[j]);

        #pragma unroll
        for (int i = 0; i < 4; ++i)
            #pragma unroll
            for (int j = 0; j < 4; ++j)
                acc[i][j] = __builtin_amdgcn_mfma_f32_16x16x32_f16(ah[i], bh[j], acc[i][j], 0, 0, 0);

        if (kt < 31) STAGEA(nxt);
        __syncthreads();
    }

    // epilogue: D[row = wm*64+i*16+lq*4+r][col = wn*64+j*16+lr]
    float* red = (float*)lds;          // [2][128] floats; buffer 0 dead
    #pragma unroll
    for (int i = 0; i < 4; ++i) {
        #pragma unroll
        for (int r = 0; r < 4; ++r) {
            const int b = lq * 4 + r;  // global row & 15
            float s = 0.f;
            #pragma unroll
            for (int j = 0; j < 4; ++j) {
                const int c = n0 + wn * 64 + j * 16 + lr;
                s += v[c] * tanhf(acc[i][j][r] + hp[b * H_SZ + c]);
            }
            s += __shfl_xor(s, 1);
            s += __shfl_xor(s, 2);
            s += __shfl_xor(s, 4);
            s += __shfl_xor(s, 8);
            if (lr == 0)
                red[wn * 128 + wm * 64 + i * 16 + lq * 4 + r] = s;
        }
    }
    __syncthreads();
    if (t < 128)
        score_part[nt * M_SZ + m0 + t] = red[t] + red[128 + t];
#undef LOADA
#undef DMAB
#undef STAGEA
}

// ---------------------------------------------------------------------------
// K3: fused softmax + context partial. Block (c,b): 64 s-steps for batch b.
// ---------------------------------------------------------------------------
__global__ __launch_bounds__(256)
void k_context_sm(const float* __restrict__ part,    // [8][32768]
                  const int* __restrict__ masks,
                  const float* __restrict__ X,
                  float* __restrict__ partial) {     // [32][16][1024]
    __shared__ float wlds[64];

    const int t = threadIdx.x;
    const int b = blockIdx.x & 15;
    const int c = blockIdx.x >> 4;

    if (t < 64) {
        const int s = c * 64 + t;
        float vals[16];
        float mx = -INFINITY;
        #pragma unroll
        for (int bb = 0; bb < 16; ++bb) {
            const int m = s * 16 + bb;
            float sc = 0.f;
            #pragma unroll
            for (int p = 0; p < 8; ++p) sc += part[p * M_SZ + m];
            sc = masks[m] ? sc : -1e10f;
            vals[bb] = sc;
            mx = fmaxf(mx, sc);
        }
        float sum = 0.f;
        #pragma unroll
        for (int bb = 0; bb < 16; ++bb) { vals[bb] = __expf(vals[bb] - mx); sum += vals[bb]; }
        wlds[t] = vals[b] / sum;
    }
    __syncthreads();

    const int h = t * 4;
    float4 acc = make_float4(0.f, 0.f, 0.f, 0.f);
    #pragma unroll 4
    for (int i = 0; i < 64; ++i) {
        float w = wlds[i];
        float4 x = *(const float4*)(X + ((size_t)((c * 64 + i) * 16 + b)) * 1024 + h);
        acc.x += w * x.x; acc.y += w * x.y; acc.z += w * x.z; acc.w += w * x.w;
    }
    *(float4*)(partial + (size_t)(c * 16 + b) * 1024 + h) = acc;
}

__global__ void k_context_reduce(const float* __restrict__ partial,
                                 float* __restrict__ out) {
    int o = blockIdx.x * blockDim.x + threadIdx.x;  // 16384
    int b = o >> 10, h = o & 1023;
    float s = 0.f;
    #pragma unroll
    for (int cc = 0; cc < 32; ++cc) s += partial[(size_t)(cc * 16 + b) * 1024 + h];
    out[o] = s;
}

extern "C" void kernel_launch(void* const* d_in, const int* in_sizes, int n_in,
                              void* d_out, int out_size, void* d_ws, size_t ws_size,
                              hipStream_t stream) {
    const float* hidden = (const float*)d_in[0];
    const float* hseq   = (const float*)d_in[1];
    const int*   masks  = (const int*)d_in[2];
    const float* W      = (const float*)d_in[3];
    const float* b_att  = (const float*)d_in[4];
    const float* v      = (const float*)d_in[5];
    float* out = (float*)d_out;

    // ws layout (float units), total 1,064,960 f = 4.06 MB:
    //   hp[16384] | score_part[8*32768] | partial[32*16*1024] | Wsw (f16 1M)
    float* wsf        = (float*)d_ws;
    float* hp         = wsf;
    float* score_part = wsf + 16384;
    float* partial    = score_part + 8 * M_SZ;
    unsigned short* Wsw = (unsigned short*)(partial + 32 * 16 * 1024);

    hipLaunchKernelGGL(k_hidden_part,    dim3(4096), dim3(256), 0, stream, hidden, W, b_att, hp);
    hipLaunchKernelGGL(k_convw,          dim3(512),  dim3(256), 0, stream, W, Wsw);
    hipLaunchKernelGGL(k_score_dma,      dim3(2048), dim3(256), 0, stream, hseq, Wsw, hp, v, score_part);
    hipLaunchKernelGGL(k_context_sm,     dim3(512),  dim3(256), 0, stream, score_part, masks, hseq, partial);
    hipLaunchKernelGGL(k_context_reduce, dim3(64),   dim3(256), 0, stream, partial, out);
}

// Round 9
// 359.052 us; speedup vs baseline: 1.0662x; 1.0662x over previous
//
#include <hip/hip_runtime.h>
#include <math.h>

// Problem constants (S=2048, B=16, H=1024)
#define S_LEN 2048
#define B_SZ  16
#define H_SZ  1024
#define M_SZ  32768

typedef __attribute__((ext_vector_type(8))) _Float16 half8;  // 4 VGPR
typedef __attribute__((ext_vector_type(4))) float f32x4;     // MFMA C/D

__device__ __forceinline__ unsigned pack2h(float a, float b) {
    _Float16 ha = (_Float16)a, hb = (_Float16)b;
    unsigned short ua = __builtin_bit_cast(unsigned short, ha);
    unsigned short ub = __builtin_bit_cast(unsigned short, hb);
    return (unsigned)ua | ((unsigned)ub << 16);
}

// Conflict-free LDS tile layout for [128 rows][32 f16] (64 B logical rows):
// row-pairs share a 128 B line; 16B-slot index XOR'd by line&7 so every
// b128 frag read covers each 128 B line exactly once (proven R7: 0 conflicts).
__device__ __forceinline__ int phys_off(int r, int sl) {
    return ((r >> 1) << 7) + ((((r & 1) << 2 | sl) ^ ((r >> 1) & 7)) << 4);
}

// async global->LDS, 16 B per lane. dest wave-uniform (HW adds lane*16).
__device__ __forceinline__ void dma16(const void* g, void* l) {
    __builtin_amdgcn_global_load_lds(
        (const __attribute__((address_space(1))) unsigned int*)g,
        (__attribute__((address_space(3))) unsigned int*)l, 16, 0, 0);
}

// ---------------------------------------------------------------------------
// K1: hp[b][h] = dot(hidden[b], W1[h]) + b_att[h]  (R2-proven)
// ---------------------------------------------------------------------------
__global__ void k_hidden_part(const float* __restrict__ hidden,
                              const float* __restrict__ W,
                              const float* __restrict__ b_att,
                              float* __restrict__ hp) {
    int gid  = blockIdx.x * blockDim.x + threadIdx.x;
    int wave = gid >> 6;
    int lane = threadIdx.x & 63;
    int b = wave >> 10;
    int h = wave & 1023;
    const float* x = hidden + b * H_SZ;
    const float* w = W + (size_t)h * (2 * H_SZ);
    float acc = 0.f;
    #pragma unroll
    for (int k = 0; k < H_SZ; k += 64) acc += x[k + lane] * w[k + lane];
    #pragma unroll
    for (int off = 32; off; off >>= 1) acc += __shfl_down(acc, off, 64);
    if (lane == 0) hp[b * H_SZ + h] = acc + b_att[h];
}

// ---------------------------------------------------------------------------
// K0: generic f32 -> fp16 pre-swizzled LDS-image tile converter.
// Tile (p, kt) is the 8 KB LDS image of rows [p*128,(p+1)*128), k [kt*32..).
// ---------------------------------------------------------------------------
__global__ void k_conv_tiles(const float* __restrict__ src,
                             unsigned short* __restrict__ dst,
                             int rowStride, int colOff) {
    int t = blockIdx.x * 256 + threadIdx.x;
    int sl = t & 3, r = (t >> 2) & 127, kt = (t >> 9) & 31, p = t >> 14;
    const float* s = src + (size_t)(p * 128 + r) * rowStride + colOff + kt * 32 + sl * 8;
    float4 f0 = *(const float4*)s;
    float4 f1 = *(const float4*)(s + 4);
    uint4 u;
    u.x = pack2h(f0.x, f0.y); u.y = pack2h(f0.z, f0.w);
    u.z = pack2h(f1.x, f1.y); u.w = pack2h(f1.z, f1.w);
    *(uint4*)((char*)dst + (size_t)(p * 32 + kt) * 8192 + phys_off(r, sl)) = u;
}

// ===========================================================================
// K2 FAST: pure-DMA fp16 MFMA GEMM + tanh + v-dot (m97 shape).
// Tile 128x128, BK=32, 256 thr = 4 waves (2x2), per-wave 64x64.
// Both A and B staged by global_load_lds from pre-swizzled tiles:
// zero in-loop conversion, zero reg staging, minimal VGPR.
// ===========================================================================
#define SA2   0
#define SB2   8192
#define SBUF2 16384

__global__ __launch_bounds__(256, 4)
void k_score_dma2(const unsigned short* __restrict__ Xsw,  // [256][32] 8KB tiles
                  const unsigned short* __restrict__ Wsw,  // [8][32] 8KB tiles
                  const float* __restrict__ hp,            // [16][1024]
                  const float* __restrict__ v,             // [1024]
                  float* __restrict__ score_part) {        // [8][32768]
    __shared__ char lds[2 * SBUF2];

    const int t = threadIdx.x;
    // XCD-chunked bijective swizzle (2048 wgs): all 8 nt of an m-panel land
    // on the same XCD chunk, temporally adjacent -> L2/L3 reuse of X.
    int wg = (blockIdx.x & 7) * 256 + (blockIdx.x >> 3);
    const int mp = wg >> 3;          // m-panel 0..255
    const int m0 = mp * 128;
    const int nt = wg & 7;
    const int n0 = nt * 128;

    const int lane = t & 63, wid = t >> 6;
    const int wm = wid >> 1, wn = wid & 1;       // 2 x 2 waves
    const int lr = lane & 15, lq = lane >> 4;

    const char* At = (const char*)Xsw + (size_t)mp * 32 * 8192 + wid * 1024 + lane * 16;
    const char* Bt = (const char*)Wsw + (size_t)nt * 32 * 8192 + wid * 1024 + lane * 16;

    int aro[4], bro[4];
    #pragma unroll
    for (int i = 0; i < 4; ++i) {
        aro[i] = phys_off(wm * 64 + i * 16 + lr, lq);
        bro[i] = phys_off(wn * 64 + i * 16 + lr, lq);
    }

    f32x4 acc[4][4];
    #pragma unroll
    for (int i = 0; i < 4; ++i)
        #pragma unroll
        for (int j = 0; j < 4; ++j) acc[i][j] = (f32x4)0.f;

#define DMA2(bufbase, kt)                                                      \
    {                                                                          \
        const char* a = At + (size_t)(kt) * 8192;                              \
        const char* b = Bt + (size_t)(kt) * 8192;                              \
        dma16(a,        (bufbase) + SA2 + wid * 1024);                         \
        dma16(a + 4096, (bufbase) + SA2 + 4096 + wid * 1024);                  \
        dma16(b,        (bufbase) + SB2 + wid * 1024);                         \
        dma16(b + 4096, (bufbase) + SB2 + 4096 + wid * 1024);                  \
    }

    DMA2(lds, 0);
    __syncthreads();

    for (int kt = 0; kt < 32; ++kt) {
        char* cur = lds + (kt & 1) * SBUF2;
        char* nxt = lds + ((kt & 1) ^ 1) * SBUF2;
        if (kt < 31) DMA2(nxt, kt + 1);

        half8 ah[4], bh[4];
        #pragma unroll
        for (int i = 0; i < 4; ++i) ah[i] = *(const half8*)(cur + SA2 + aro[i]);
        #pragma unroll
        for (int j = 0; j < 4; ++j) bh[j] = *(const half8*)(cur + SB2 + bro[j]);

        #pragma unroll
        for (int i = 0; i < 4; ++i)
            #pragma unroll
            for (int j = 0; j < 4; ++j)
                acc[i][j] = __builtin_amdgcn_mfma_f32_16x16x32_f16(ah[i], bh[j], acc[i][j], 0, 0, 0);

        __syncthreads();
    }

    // epilogue: D[row = wm*64+i*16+lq*4+r][col = wn*64+j*16+lr]
    float* red = (float*)lds;
    #pragma unroll
    for (int i = 0; i < 4; ++i) {
        #pragma unroll
        for (int r = 0; r < 4; ++r) {
            const int b = lq * 4 + r;  // global row & 15
            float s = 0.f;
            #pragma unroll
            for (int j = 0; j < 4; ++j) {
                const int c = n0 + wn * 64 + j * 16 + lr;
                s += v[c] * tanhf(acc[i][j][r] + hp[b * H_SZ + c]);
            }
            s += __shfl_xor(s, 1);
            s += __shfl_xor(s, 2);
            s += __shfl_xor(s, 4);
            s += __shfl_xor(s, 8);
            if (lr == 0)
                red[wn * 128 + wm * 64 + i * 16 + lq * 4 + r] = s;
        }
    }
    __syncthreads();
    if (t < 128)
        score_part[nt * M_SZ + m0 + t] = red[t] + red[128 + t];
#undef DMA2
}

// ===========================================================================
// K2 FALLBACK (proven R7): A reg-staged f32->f16, B via DMA from Wsw
// ===========================================================================
__global__ __launch_bounds__(256, 3)
void k_score_dma(const float* __restrict__ X,
                 const unsigned short* __restrict__ Wsw,
                 const float* __restrict__ hp,
                 const float* __restrict__ v,
                 float* __restrict__ score_part) {
    __shared__ char lds[2 * SBUF2];

    const int t = threadIdx.x;
    int wg = (blockIdx.x & 7) * 256 + (blockIdx.x >> 3);
    const int m0 = (wg >> 3) * 128;
    const int nt = wg & 7;
    const int n0 = nt * 128;

    const int lane = t & 63, wid = t >> 6;
    const int wm = wid >> 1, wn = wid & 1;
    const int lr = lane & 15, lq = lane >> 4;

    const int srow = t >> 1, shalf = t & 1;
    const float* Xp = X + (size_t)(m0 + srow) * 1024 + shalf * 16;
    const int aOff0 = phys_off(srow, shalf * 2 + 0);
    const int aOff1 = phys_off(srow, shalf * 2 + 1);

    const unsigned short* Bp = Wsw + (size_t)(nt * 32) * 4096 + wid * 512 + lane * 8;

    int aro[4], bro[4];
    #pragma unroll
    for (int i = 0; i < 4; ++i) {
        aro[i] = phys_off(wm * 64 + i * 16 + lr, lq);
        bro[i] = phys_off(wn * 64 + i * 16 + lr, lq);
    }

    f32x4 acc[4][4];
    #pragma unroll
    for (int i = 0; i < 4; ++i)
        #pragma unroll
        for (int j = 0; j < 4; ++j) acc[i][j] = (f32x4)0.f;

    float4 ax[4];

#define LOADA(kt)                                                              \
    {                                                                          \
        const float* p = Xp + (kt) * 32;                                       \
        ax[0] = *(const float4*)(p);                                           \
        ax[1] = *(const float4*)(p + 4);                                       \
        ax[2] = *(const float4*)(p + 8);                                       \
        ax[3] = *(const float4*)(p + 12);                                      \
    }

#define DMAB(bufbase, kt)                                                      \
    {                                                                          \
        const unsigned short* s0 = Bp + (size_t)(kt) * 4096;                   \
        dma16(s0,        (bufbase) + SB2 + wid * 1024);                        \
        dma16(s0 + 2048, (bufbase) + SB2 + wid * 1024 + 4096);                 \
    }

#define STAGEA(bufbase)                                                        \
    {                                                                          \
        uint4 p0, p1;                                                          \
        p0.x = pack2h(ax[0].x, ax[0].y); p0.y = pack2h(ax[0].z, ax[0].w);      \
        p0.z = pack2h(ax[1].x, ax[1].y); p0.w = pack2h(ax[1].z, ax[1].w);      \
        p1.x = pack2h(ax[2].x, ax[2].y); p1.y = pack2h(ax[2].z, ax[2].w);      \
        p1.z = pack2h(ax[3].x, ax[3].y); p1.w = pack2h(ax[3].z, ax[3].w);      \
        *(uint4*)((bufbase) + SA2 + aOff0) = p0;                               \
        *(uint4*)((bufbase) + SA2 + aOff1) = p1;                               \
    }

    LOADA(0);
    DMAB(lds, 0);
    STAGEA(lds);
    __syncthreads();

    for (int kt = 0; kt < 32; ++kt) {
        char* cur = lds + (kt & 1) * SBUF2;
        char* nxt = lds + ((kt & 1) ^ 1) * SBUF2;
        if (kt < 31) {
            LOADA(kt + 1);
            DMAB(nxt, kt + 1);
        }

        half8 ah[4], bh[4];
        #pragma unroll
        for (int i = 0; i < 4; ++i) ah[i] = *(const half8*)(cur + SA2 + aro[i]);
        #pragma unroll
        for (int j = 0; j < 4; ++j) bh[j] = *(const half8*)(cur + SB2 + bro[j]);

        #pragma unroll
        for (int i = 0; i < 4; ++i)
            #pragma unroll
            for (int j = 0; j < 4; ++j)
                acc[i][j] = __builtin_amdgcn_mfma_f32_16x16x32_f16(ah[i], bh[j], acc[i][j], 0, 0, 0);

        if (kt < 31) STAGEA(nxt);
        __syncthreads();
    }

    float* red = (float*)lds;
    #pragma unroll
    for (int i = 0; i < 4; ++i) {
        #pragma unroll
        for (int r = 0; r < 4; ++r) {
            const int b = lq * 4 + r;
            float s = 0.f;
            #pragma unroll
            for (int j = 0; j < 4; ++j) {
                const int c = n0 + wn * 64 + j * 16 + lr;
                s += v[c] * tanhf(acc[i][j][r] + hp[b * H_SZ + c]);
            }
            s += __shfl_xor(s, 1);
            s += __shfl_xor(s, 2);
            s += __shfl_xor(s, 4);
            s += __shfl_xor(s, 8);
            if (lr == 0)
                red[wn * 128 + wm * 64 + i * 16 + lq * 4 + r] = s;
        }
    }
    __syncthreads();
    if (t < 128)
        score_part[nt * M_SZ + m0 + t] = red[t] + red[128 + t];
#undef LOADA
#undef DMAB
#undef STAGEA
}

// ---------------------------------------------------------------------------
// K3: fold 8 partials, mask, softmax over b -> wts  (R2-proven structure)
// ---------------------------------------------------------------------------
__global__ void k_softmax(const float* __restrict__ part,
                          const int* __restrict__ masks,
                          float* __restrict__ wts) {
    int s = blockIdx.x * blockDim.x + threadIdx.x;
    if (s >= S_LEN) return;
    float vals[16];
    float mx = -INFINITY;
    #pragma unroll
    for (int b = 0; b < 16; ++b) {
        int m = s * 16 + b;
        float sc = 0.f;
        #pragma unroll
        for (int p = 0; p < 8; ++p) sc += part[p * M_SZ + m];
        sc = masks[m] ? sc : -1e10f;
        vals[b] = sc;
        mx = fmaxf(mx, sc);
    }
    float sum = 0.f;
    #pragma unroll
    for (int b = 0; b < 16; ++b) { vals[b] = __expf(vals[b] - mx); sum += vals[b]; }
    float inv = 1.f / sum;
    #pragma unroll
    for (int b = 0; b < 16; ++b) wts[s * 16 + b] = vals[b] * inv;
}

// ---------------------------------------------------------------------------
// K4a/K4b: context (R2-proven): partial sums over 16 s-chunks, then reduce.
// ---------------------------------------------------------------------------
__global__ void k_context_partial(const float* __restrict__ wts,
                                  const float* __restrict__ X,
                                  float* __restrict__ partial) {
    int b = blockIdx.x & 15;
    int c = blockIdx.x >> 4;
    int h = threadIdx.x * 4;
    float4 acc = make_float4(0.f, 0.f, 0.f, 0.f);
    for (int s = c * 128; s < c * 128 + 128; ++s) {
        float w = wts[s * 16 + b];
        float4 x = *(const float4*)(X + (size_t)(s * 16 + b) * 1024 + h);
        acc.x += w * x.x; acc.y += w * x.y; acc.z += w * x.z; acc.w += w * x.w;
    }
    *(float4*)(partial + (size_t)(c * 16 + b) * 1024 + h) = acc;
}

__global__ void k_context_reduce(const float* __restrict__ partial,
                                 float* __restrict__ out) {
    int o = blockIdx.x * blockDim.x + threadIdx.x;  // 16384
    int b = o >> 10, h = o & 1023;
    float s = 0.f;
    #pragma unroll
    for (int cc = 0; cc < 16; ++cc) s += partial[(size_t)(cc * 16 + b) * 1024 + h];
    out[o] = s;
}

extern "C" void kernel_launch(void* const* d_in, const int* in_sizes, int n_in,
                              void* d_out, int out_size, void* d_ws, size_t ws_size,
                              hipStream_t stream) {
    const float* hidden = (const float*)d_in[0];
    const float* hseq   = (const float*)d_in[1];
    const int*   masks  = (const int*)d_in[2];
    const float* W      = (const float*)d_in[3];
    const float* b_att  = (const float*)d_in[4];
    const float* v      = (const float*)d_in[5];
    float* out = (float*)d_out;

    // ws layout (float units):
    //   hp[16384] | wts[32768] | score_part[8*32768] | partial[16*16*1024]
    //   | Wsw[2MB=524288f] | Xsw[64MB=16777216f]   (Xsw only in fast path)
    float* wsf        = (float*)d_ws;
    float* hp         = wsf;
    float* wts        = wsf + 16384;
    float* score_part = wts + 32768;
    float* partial    = score_part + 8 * M_SZ;
    unsigned short* Wsw = (unsigned short*)(partial + 262144);
    unsigned short* Xsw = (unsigned short*)((char*)Wsw + 2 * 1024 * 1024);
    const size_t WS_FAST = (size_t)(16384 + 32768 + 262144 + 262144) * 4
                         + 2ull * 1024 * 1024 + 64ull * 1024 * 1024;

    hipLaunchKernelGGL(k_hidden_part, dim3(4096), dim3(256), 0, stream, hidden, W, b_att, hp);
    hipLaunchKernelGGL(k_conv_tiles,  dim3(512),  dim3(256), 0, stream, W, Wsw, 2048, 1024);
    if (ws_size >= WS_FAST) {
        hipLaunchKernelGGL(k_conv_tiles,  dim3(16384), dim3(256), 0, stream, hseq, Xsw, 1024, 0);
        hipLaunchKernelGGL(k_score_dma2,  dim3(2048),  dim3(256), 0, stream, Xsw, Wsw, hp, v, score_part);
    } else {
        hipLaunchKernelGGL(k_score_dma,   dim3(2048),  dim3(256), 0, stream, hseq, Wsw, hp, v, score_part);
    }
    hipLaunchKernelGGL(k_softmax,         dim3(8),   dim3(256), 0, stream, score_part, masks, wts);
    hipLaunchKernelGGL(k_context_partial, dim3(256), dim3(256), 0, stream, wts, hseq, partial);
    hipLaunchKernelGGL(k_context_reduce,  dim3(64),  dim3(256), 0, stream, partial, out);
}

// Round 10
// 334.066 us; speedup vs baseline: 1.1460x; 1.0748x over previous
//
#include <hip/hip_runtime.h>
#include <math.h>

// Problem constants (S=2048, B=16, H=1024)
#define S_LEN 2048
#define B_SZ  16
#define H_SZ  1024
#define M_SZ  32768

typedef __attribute__((ext_vector_type(8))) _Float16 half8;  // 4 VGPR
typedef __attribute__((ext_vector_type(4))) _Float16 half4;  // 8 B
typedef __attribute__((ext_vector_type(4))) float f32x4;     // MFMA C/D

__device__ __forceinline__ unsigned pack2h(float a, float b) {
    _Float16 ha = (_Float16)a, hb = (_Float16)b;
    unsigned short ua = __builtin_bit_cast(unsigned short, ha);
    unsigned short ub = __builtin_bit_cast(unsigned short, hb);
    return (unsigned)ua | ((unsigned)ub << 16);
}

// fast tanh: 1 - 2/(e^{2x}+1); exact at +-inf saturation, ~1e-6 rel err
__device__ __forceinline__ float tanh_fast(float x) {
    float e = __expf(2.f * x);
    return __builtin_fmaf(-2.f, __builtin_amdgcn_rcpf(e + 1.f), 1.f);
}

// Conflict-free LDS tile layout for [128 rows][32 f16] (64 B logical rows):
// row-pairs share a 128 B line; 16B-slot XOR'd by line&7 (proven: 0 conflicts).
__device__ __forceinline__ int phys_off(int r, int sl) {
    return ((r >> 1) << 7) + ((((r & 1) << 2 | sl) ^ ((r >> 1) & 7)) << 4);
}

// async global->LDS, 16 B per lane. dest wave-uniform (HW adds lane*16).
__device__ __forceinline__ void dma16(const void* g, void* l) {
    __builtin_amdgcn_global_load_lds(
        (const __attribute__((address_space(1))) unsigned int*)g,
        (__attribute__((address_space(3))) unsigned int*)l, 16, 0, 0);
}

// ---------------------------------------------------------------------------
// K1: hp[b][h] = dot(hidden[b], W1[h]) + b_att[h]  (R2-proven)
// ---------------------------------------------------------------------------
__global__ void k_hidden_part(const float* __restrict__ hidden,
                              const float* __restrict__ W,
                              const float* __restrict__ b_att,
                              float* __restrict__ hp) {
    int gid  = blockIdx.x * blockDim.x + threadIdx.x;
    int wave = gid >> 6;
    int lane = threadIdx.x & 63;
    int b = wave >> 10;
    int h = wave & 1023;
    const float* x = hidden + b * H_SZ;
    const float* w = W + (size_t)h * (2 * H_SZ);
    float acc = 0.f;
    #pragma unroll
    for (int k = 0; k < H_SZ; k += 64) acc += x[k + lane] * w[k + lane];
    #pragma unroll
    for (int off = 32; off; off >>= 1) acc += __shfl_down(acc, off, 64);
    if (lane == 0) hp[b * H_SZ + h] = acc + b_att[h];
}

// ---------------------------------------------------------------------------
// K0: f32 -> fp16 pre-swizzled LDS-image tile converter (proven R9).
// ---------------------------------------------------------------------------
__global__ void k_conv_tiles(const float* __restrict__ src,
                             unsigned short* __restrict__ dst,
                             int rowStride, int colOff) {
    int t = blockIdx.x * 256 + threadIdx.x;
    int sl = t & 3, r = (t >> 2) & 127, kt = (t >> 9) & 31, p = t >> 14;
    const float* s = src + (size_t)(p * 128 + r) * rowStride + colOff + kt * 32 + sl * 8;
    float4 f0 = *(const float4*)s;
    float4 f1 = *(const float4*)(s + 4);
    uint4 u;
    u.x = pack2h(f0.x, f0.y); u.y = pack2h(f0.z, f0.w);
    u.z = pack2h(f1.x, f1.y); u.w = pack2h(f1.z, f1.w);
    *(uint4*)((char*)dst + (size_t)(p * 32 + kt) * 8192 + phys_off(r, sl)) = u;
}

// ===========================================================================
// K2 FAST: pure-DMA fp16 MFMA GEMM, PIPELINED (T3+T4+T5):
// triple-buffered LDS, DMA issued 2 tiles ahead AFTER a raw s_barrier,
// counted s_waitcnt vmcnt(4) (never 0 in the main loop).
// Safety: each wave drains ITS tile-kt DMAs (vmcnt<=4) BEFORE the barrier,
// so post-barrier all waves' tile-kt data is in LDS; the buffer overwritten
// by DMA(kt+2) was last read at kt-1, and every wave passed barrier(kt)
// after finishing those reads (MFMA issue implies ds_read completion).
// ===========================================================================
#define SA2   0
#define SB2   8192
#define SBUF2 16384

__global__ __launch_bounds__(256, 3)
void k_score_pipe(const unsigned short* __restrict__ Xsw,  // [256][32] 8KB tiles
                  const unsigned short* __restrict__ Wsw,  // [8][32] 8KB tiles
                  const float* __restrict__ hp,            // [16][1024]
                  const float* __restrict__ v,             // [1024]
                  float* __restrict__ score_part) {        // [32768][8] interleaved
    __shared__ char lds[3 * SBUF2];   // 48 KB

    const int t = threadIdx.x;
    int wg = (blockIdx.x & 7) * 256 + (blockIdx.x >> 3);  // XCD-chunked swizzle
    const int mp = wg >> 3;
    const int m0 = mp * 128;
    const int nt = wg & 7;
    const int n0 = nt * 128;

    const int lane = t & 63, wid = t >> 6;
    const int wm = wid >> 1, wn = wid & 1;
    const int lr = lane & 15, lq = lane >> 4;

    const char* At = (const char*)Xsw + (size_t)mp * 32 * 8192 + wid * 1024 + lane * 16;
    const char* Bt = (const char*)Wsw + (size_t)nt * 32 * 8192 + wid * 1024 + lane * 16;

    int aro[4], bro[4];
    #pragma unroll
    for (int i = 0; i < 4; ++i) {
        aro[i] = phys_off(wm * 64 + i * 16 + lr, lq);
        bro[i] = phys_off(wn * 64 + i * 16 + lr, lq);
    }

    f32x4 acc[4][4];
    #pragma unroll
    for (int i = 0; i < 4; ++i)
        #pragma unroll
        for (int j = 0; j < 4; ++j) acc[i][j] = (f32x4)0.f;

#define DMA2(bufbase, kt)                                                      \
    {                                                                          \
        const char* a = At + (size_t)(kt) * 8192;                              \
        const char* b = Bt + (size_t)(kt) * 8192;                              \
        dma16(a,        (bufbase) + SA2 + wid * 1024);                         \
        dma16(a + 4096, (bufbase) + SA2 + 4096 + wid * 1024);                  \
        dma16(b,        (bufbase) + SB2 + wid * 1024);                         \
        dma16(b + 4096, (bufbase) + SB2 + 4096 + wid * 1024);                  \
    }

    char* cb0 = lds;                 // tile kt
    char* cb1 = lds + SBUF2;         // tile kt+1
    char* cb2 = lds + 2 * SBUF2;     // free / tile kt+2
    DMA2(cb0, 0);
    DMA2(cb1, 1);

    for (int kt = 0; kt < 32; ++kt) {
        if (kt < 31) { asm volatile("s_waitcnt vmcnt(4)" ::: "memory"); }
        else         { asm volatile("s_waitcnt vmcnt(0)" ::: "memory"); }
        __builtin_amdgcn_s_barrier();
        __builtin_amdgcn_sched_barrier(0);   // pin: no motion across barrier
        if (kt < 30) DMA2(cb2, kt + 2);

        half8 ah[4], bh[4];
        #pragma unroll
        for (int i = 0; i < 4; ++i) ah[i] = *(const half8*)(cb0 + SA2 + aro[i]);
        #pragma unroll
        for (int j = 0; j < 4; ++j) bh[j] = *(const half8*)(cb0 + SB2 + bro[j]);

        __builtin_amdgcn_s_setprio(1);
        #pragma unroll
        for (int i = 0; i < 4; ++i)
            #pragma unroll
            for (int j = 0; j < 4; ++j)
                acc[i][j] = __builtin_amdgcn_mfma_f32_16x16x32_f16(ah[i], bh[j], acc[i][j], 0, 0, 0);
        __builtin_amdgcn_s_setprio(0);

        char* tmp = cb0; cb0 = cb1; cb1 = cb2; cb2 = tmp;
    }
    __syncthreads();   // all reads done before red overlay

    // epilogue: D[row = wm*64+i*16+lq*4+r][col = wn*64+j*16+lr]
    float* red = (float*)lds;
    #pragma unroll
    for (int i = 0; i < 4; ++i) {
        #pragma unroll
        for (int r = 0; r < 4; ++r) {
            const int b = lq * 4 + r;  // global row & 15
            float s = 0.f;
            #pragma unroll
            for (int j = 0; j < 4; ++j) {
                const int c = n0 + wn * 64 + j * 16 + lr;
                s += v[c] * tanh_fast(acc[i][j][r] + hp[b * H_SZ + c]);
            }
            s += __shfl_xor(s, 1);
            s += __shfl_xor(s, 2);
            s += __shfl_xor(s, 4);
            s += __shfl_xor(s, 8);
            if (lr == 0)
                red[wn * 128 + wm * 64 + i * 16 + lq * 4 + r] = s;
        }
    }
    __syncthreads();
    if (t < 128)
        score_part[(size_t)(m0 + t) * 8 + nt] = red[t] + red[128 + t];
#undef DMA2
}

// ===========================================================================
// K2 FALLBACK (R7-proven; write layout updated to [m][8])
// ===========================================================================
__global__ __launch_bounds__(256, 3)
void k_score_dma(const float* __restrict__ X,
                 const unsigned short* __restrict__ Wsw,
                 const float* __restrict__ hp,
                 const float* __restrict__ v,
                 float* __restrict__ score_part) {
    __shared__ char lds[2 * SBUF2];

    const int t = threadIdx.x;
    int wg = (blockIdx.x & 7) * 256 + (blockIdx.x >> 3);
    const int m0 = (wg >> 3) * 128;
    const int nt = wg & 7;
    const int n0 = nt * 128;

    const int lane = t & 63, wid = t >> 6;
    const int wm = wid >> 1, wn = wid & 1;
    const int lr = lane & 15, lq = lane >> 4;

    const int srow = t >> 1, shalf = t & 1;
    const float* Xp = X + (size_t)(m0 + srow) * 1024 + shalf * 16;
    const int aOff0 = phys_off(srow, shalf * 2 + 0);
    const int aOff1 = phys_off(srow, shalf * 2 + 1);

    const unsigned short* Bp = Wsw + (size_t)(nt * 32) * 4096 + wid * 512 + lane * 8;

    int aro[4], bro[4];
    #pragma unroll
    for (int i = 0; i < 4; ++i) {
        aro[i] = phys_off(wm * 64 + i * 16 + lr, lq);
        bro[i] = phys_off(wn * 64 + i * 16 + lr, lq);
    }

    f32x4 acc[4][4];
    #pragma unroll
    for (int i = 0; i < 4; ++i)
        #pragma unroll
        for (int j = 0; j < 4; ++j) acc[i][j] = (f32x4)0.f;

    float4 ax[4];

#define LOADA(kt)                                                              \
    {                                                                          \
        const float* p = Xp + (kt) * 32;                                       \
        ax[0] = *(const float4*)(p);                                           \
        ax[1] = *(const float4*)(p + 4);                                       \
        ax[2] = *(const float4*)(p + 8);                                       \
        ax[3] = *(const float4*)(p + 12);                                      \
    }

#define DMAB(bufbase, kt)                                                      \
    {                                                                          \
        const unsigned short* s0 = Bp + (size_t)(kt) * 4096;                   \
        dma16(s0,        (bufbase) + SB2 + wid * 1024);                        \
        dma16(s0 + 2048, (bufbase) + SB2 + wid * 1024 + 4096);                 \
    }

#define STAGEA(bufbase)                                                        \
    {                                                                          \
        uint4 p0, p1;                                                          \
        p0.x = pack2h(ax[0].x, ax[0].y); p0.y = pack2h(ax[0].z, ax[0].w);      \
        p0.z = pack2h(ax[1].x, ax[1].y); p0.w = pack2h(ax[1].z, ax[1].w);      \
        p1.x = pack2h(ax[2].x, ax[2].y); p1.y = pack2h(ax[2].z, ax[2].w);      \
        p1.z = pack2h(ax[3].x, ax[3].y); p1.w = pack2h(ax[3].z, ax[3].w);      \
        *(uint4*)((bufbase) + SA2 + aOff0) = p0;                               \
        *(uint4*)((bufbase) + SA2 + aOff1) = p1;                               \
    }

    LOADA(0);
    DMAB(lds, 0);
    STAGEA(lds);
    __syncthreads();

    for (int kt = 0; kt < 32; ++kt) {
        char* cur = lds + (kt & 1) * SBUF2;
        char* nxt = lds + ((kt & 1) ^ 1) * SBUF2;
        if (kt < 31) {
            LOADA(kt + 1);
            DMAB(nxt, kt + 1);
        }

        half8 ah[4], bh[4];
        #pragma unroll
        for (int i = 0; i < 4; ++i) ah[i] = *(const half8*)(cur + SA2 + aro[i]);
        #pragma unroll
        for (int j = 0; j < 4; ++j) bh[j] = *(const half8*)(cur + SB2 + bro[j]);

        #pragma unroll
        for (int i = 0; i < 4; ++i)
            #pragma unroll
            for (int j = 0; j < 4; ++j)
                acc[i][j] = __builtin_amdgcn_mfma_f32_16x16x32_f16(ah[i], bh[j], acc[i][j], 0, 0, 0);

        if (kt < 31) STAGEA(nxt);
        __syncthreads();
    }

    float* red = (float*)lds;
    #pragma unroll
    for (int i = 0; i < 4; ++i) {
        #pragma unroll
        for (int r = 0; r < 4; ++r) {
            const int b = lq * 4 + r;
            float s = 0.f;
            #pragma unroll
            for (int j = 0; j < 4; ++j) {
                const int c = n0 + wn * 64 + j * 16 + lr;
                s += v[c] * tanh_fast(acc[i][j][r] + hp[b * H_SZ + c]);
            }
            s += __shfl_xor(s, 1);
            s += __shfl_xor(s, 2);
            s += __shfl_xor(s, 4);
            s += __shfl_xor(s, 8);
            if (lr == 0)
                red[wn * 128 + wm * 64 + i * 16 + lq * 4 + r] = s;
        }
    }
    __syncthreads();
    if (t < 128)
        score_part[(size_t)(m0 + t) * 8 + nt] = red[t] + red[128 + t];
#undef LOADA
#undef DMAB
#undef STAGEA
}

// ---------------------------------------------------------------------------
// K3: fold 8 CONTIGUOUS partials per (s,b), mask, softmax over b -> wts.
// score_part layout [m][8]: per-thread reads are 128 contiguous floats.
// ---------------------------------------------------------------------------
__global__ void k_softmax(const float* __restrict__ sp,
                          const int* __restrict__ masks,
                          float* __restrict__ wts) {
    int s = blockIdx.x * blockDim.x + threadIdx.x;
    if (s >= S_LEN) return;
    const float4* base = (const float4*)(sp + (size_t)s * 128);
    float vals[16];
    float mx = -INFINITY;
    #pragma unroll
    for (int b = 0; b < 16; ++b) {
        float4 p0 = base[b * 2], p1 = base[b * 2 + 1];
        float sc = ((p0.x + p0.y) + (p0.z + p0.w)) + ((p1.x + p1.y) + (p1.z + p1.w));
        sc = masks[s * 16 + b] ? sc : -1e10f;
        vals[b] = sc;
        mx = fmaxf(mx, sc);
    }
    float sum = 0.f;
    #pragma unroll
    for (int b = 0; b < 16; ++b) { vals[b] = __expf(vals[b] - mx); sum += vals[b]; }
    float inv = 1.f / sum;
    #pragma unroll
    for (int b = 0; b < 16; ++b) wts[s * 16 + b] = vals[b] * inv;
}

// ---------------------------------------------------------------------------
// K4a FAST: context partials from f16 Xsw (cache-hot, half the bytes).
// Block (c,b), c in 0..31, 64 s-steps; thread t covers h = 4t..4t+3.
// ---------------------------------------------------------------------------
__global__ __launch_bounds__(256)
void k_context_f16(const float* __restrict__ wts,
                   const unsigned short* __restrict__ Xsw,
                   float* __restrict__ partial) {     // [32][16][1024]
    const int t = threadIdx.x;
    const int b = blockIdx.x & 15;
    const int c = blockIdx.x >> 4;
    const int kt = t >> 3;
    const int sl = (t >> 1) & 3;
    const int e8 = (t & 1) * 8;

    int po[8];
    #pragma unroll
    for (int j = 0; j < 8; ++j) po[j] = phys_off(b + j * 16, sl) + e8;

    const char* base = (const char*)Xsw + ((size_t)(c * 8) * 32 + kt) * 8192;
    float4 acc = make_float4(0.f, 0.f, 0.f, 0.f);
    #pragma unroll
    for (int o = 0; o < 8; ++o) {
        const char* tb = base + (size_t)o * 32 * 8192;
        #pragma unroll
        for (int j = 0; j < 8; ++j) {
            const int s = c * 64 + o * 8 + j;
            float w = wts[s * 16 + b];
            half4 x = *(const half4*)(tb + po[j]);
            acc.x += w * (float)x[0];
            acc.y += w * (float)x[1];
            acc.z += w * (float)x[2];
            acc.w += w * (float)x[3];
        }
    }
    *(float4*)(partial + (size_t)(c * 16 + b) * 1024 + t * 4) = acc;
}

// K4a FALLBACK: f32 X, 32 chunks of 64 s.
__global__ void k_context_partial(const float* __restrict__ wts,
                                  const float* __restrict__ X,
                                  float* __restrict__ partial) {
    int b = blockIdx.x & 15;
    int c = blockIdx.x >> 4;
    int h = threadIdx.x * 4;
    float4 acc = make_float4(0.f, 0.f, 0.f, 0.f);
    for (int s = c * 64; s < c * 64 + 64; ++s) {
        float w = wts[s * 16 + b];
        float4 x = *(const float4*)(X + (size_t)(s * 16 + b) * 1024 + h);
        acc.x += w * x.x; acc.y += w * x.y; acc.z += w * x.z; acc.w += w * x.w;
    }
    *(float4*)(partial + (size_t)(c * 16 + b) * 1024 + h) = acc;
}

__global__ void k_context_reduce(const float* __restrict__ partial,
                                 float* __restrict__ out) {
    int o = blockIdx.x * blockDim.x + threadIdx.x;  // 16384
    int b = o >> 10, h = o & 1023;
    float s = 0.f;
    #pragma unroll
    for (int cc = 0; cc < 32; ++cc) s += partial[(size_t)(cc * 16 + b) * 1024 + h];
    out[o] = s;
}

extern "C" void kernel_launch(void* const* d_in, const int* in_sizes, int n_in,
                              void* d_out, int out_size, void* d_ws, size_t ws_size,
                              hipStream_t stream) {
    const float* hidden = (const float*)d_in[0];
    const float* hseq   = (const float*)d_in[1];
    const int*   masks  = (const int*)d_in[2];
    const float* W      = (const float*)d_in[3];
    const float* b_att  = (const float*)d_in[4];
    const float* v      = (const float*)d_in[5];
    float* out = (float*)d_out;

    // ws layout (float units):
    //   hp[16384] | wts[32768] | score_part[32768*8] | partial[32*16*1024]
    //   | Wsw[2MB] | Xsw[64MB]
    float* wsf        = (float*)d_ws;
    float* hp         = wsf;
    float* wts        = wsf + 16384;
    float* score_part = wts + 32768;
    float* partial    = score_part + 8 * M_SZ;
    unsigned short* Wsw = (unsigned short*)(partial + 32 * 16 * 1024);
    unsigned short* Xsw = (unsigned short*)((char*)Wsw + 2 * 1024 * 1024);
    const size_t WS_FAST = (size_t)(16384 + 32768 + 262144 + 524288) * 4
                         + 2ull * 1024 * 1024 + 64ull * 1024 * 1024;

    hipLaunchKernelGGL(k_hidden_part, dim3(4096), dim3(256), 0, stream, hidden, W, b_att, hp);
    hipLaunchKernelGGL(k_conv_tiles,  dim3(512),  dim3(256), 0, stream, W, Wsw, 2048, 1024);
    if (ws_size >= WS_FAST) {
        hipLaunchKernelGGL(k_conv_tiles,   dim3(16384), dim3(256), 0, stream, hseq, Xsw, 1024, 0);
        hipLaunchKernelGGL(k_score_pipe,   dim3(2048),  dim3(256), 0, stream, Xsw, Wsw, hp, v, score_part);
        hipLaunchKernelGGL(k_softmax,      dim3(8),     dim3(256), 0, stream, score_part, masks, wts);
        hipLaunchKernelGGL(k_context_f16,  dim3(512),   dim3(256), 0, stream, wts, Xsw, partial);
    } else {
        hipLaunchKernelGGL(k_score_dma,    dim3(2048),  dim3(256), 0, stream, hseq, Wsw, hp, v, score_part);
        hipLaunchKernelGGL(k_softmax,      dim3(8),     dim3(256), 0, stream, score_part, masks, wts);
        hipLaunchKernelGGL(k_context_partial, dim3(512), dim3(256), 0, stream, wts, hseq, partial);
    }
    hipLaunchKernelGGL(k_context_reduce, dim3(64), dim3(256), 0, stream, partial, out);
}

// Round 12
// 322.078 us; speedup vs baseline: 1.1887x; 1.0372x over previous
//
#include <hip/hip_runtime.h>
#include <math.h>

// Problem constants (S=2048, B=16, H=1024)
#define S_LEN 2048
#define B_SZ  16
#define H_SZ  1024
#define M_SZ  32768

typedef __attribute__((ext_vector_type(8))) _Float16 half8;  // 4 VGPR
typedef __attribute__((ext_vector_type(4))) _Float16 half4;  // 8 B
typedef __attribute__((ext_vector_type(4))) float f32x4;     // MFMA C/D

__device__ __forceinline__ unsigned pack2h(float a, float b) {
    _Float16 ha = (_Float16)a, hb = (_Float16)b;
    unsigned short ua = __builtin_bit_cast(unsigned short, ha);
    unsigned short ub = __builtin_bit_cast(unsigned short, hb);
    return (unsigned)ua | ((unsigned)ub << 16);
}

// fast tanh: 1 - 2/(e^{2x}+1); saturates correctly, ~1e-6 rel err (R10-proven)
__device__ __forceinline__ float tanh_fast(float x) {
    float e = __expf(2.f * x);
    return __builtin_fmaf(-2.f, __builtin_amdgcn_rcpf(e + 1.f), 1.f);
}

// Conflict-free LDS tile layout for [128 rows][32 f16] (proven: 0 conflicts).
__device__ __forceinline__ int phys_off(int r, int sl) {
    return ((r >> 1) << 7) + ((((r & 1) << 2 | sl) ^ ((r >> 1) & 7)) << 4);
}

// async global->LDS, 16 B per lane. dest wave-uniform (HW adds lane*16).
__device__ __forceinline__ void dma16(const void* g, void* l) {
    __builtin_amdgcn_global_load_lds(
        (const __attribute__((address_space(1))) unsigned int*)g,
        (__attribute__((address_space(3))) unsigned int*)l, 16, 0, 0);
}

// ---------------------------------------------------------------------------
// K1: hp[b][h] = dot(hidden[b], W1[h]) + b_att[h]  (R2-proven)  +  FUSED
// W2-row conversion: waves with b==0 also emit the pre-swizzled f16 image
// of W2 row h (saves the separate convW launch).
// ---------------------------------------------------------------------------
__global__ void k_hidden_conv(const float* __restrict__ hidden,
                              const float* __restrict__ W,
                              const float* __restrict__ b_att,
                              float* __restrict__ hp,
                              unsigned short* __restrict__ Wsw) {
    int gid  = blockIdx.x * blockDim.x + threadIdx.x;
    int wave = gid >> 6;
    int lane = threadIdx.x & 63;
    int b = wave >> 10;
    int h = wave & 1023;
    const float* x = hidden + b * H_SZ;
    const float* w = W + (size_t)h * (2 * H_SZ);
    float acc = 0.f;
    #pragma unroll
    for (int k = 0; k < H_SZ; k += 64) acc += x[k + lane] * w[k + lane];
    #pragma unroll
    for (int off = 32; off; off >>= 1) acc += __shfl_down(acc, off, 64);
    if (lane == 0) hp[b * H_SZ + h] = acc + b_att[h];

    if (b == 0) {   // wave-uniform: convert W2 row h (1024 f32 -> f16 image)
        const int p = h >> 7, r = h & 127;
        const float* src = W + (size_t)h * 2048 + 1024;
        #pragma unroll
        for (int q = 0; q < 2; ++q) {
            int slot = lane + q * 64;          // 0..127
            int kt = slot >> 2, sl = slot & 3;
            const float* s8 = src + kt * 32 + sl * 8;
            float4 f0 = *(const float4*)s8;
            float4 f1 = *(const float4*)(s8 + 4);
            uint4 u;
            u.x = pack2h(f0.x, f0.y); u.y = pack2h(f0.z, f0.w);
            u.z = pack2h(f1.x, f1.y); u.w = pack2h(f1.z, f1.w);
            *(uint4*)((char*)Wsw + (size_t)(p * 32 + kt) * 8192 + phys_off(r, sl)) = u;
        }
    }
}

// ---------------------------------------------------------------------------
// K0: X f32 -> fp16 pre-swizzled LDS-image tiles (proven R9/R10).
// ---------------------------------------------------------------------------
__global__ void k_conv_tiles(const float* __restrict__ src,
                             unsigned short* __restrict__ dst,
                             int rowStride, int colOff) {
    int t = blockIdx.x * 256 + threadIdx.x;
    int sl = t & 3, r = (t >> 2) & 127, kt = (t >> 9) & 31, p = t >> 14;
    const float* s = src + (size_t)(p * 128 + r) * rowStride + colOff + kt * 32 + sl * 8;
    float4 f0 = *(const float4*)s;
    float4 f1 = *(const float4*)(s + 4);
    uint4 u;
    u.x = pack2h(f0.x, f0.y); u.y = pack2h(f0.z, f0.w);
    u.z = pack2h(f1.x, f1.y); u.w = pack2h(f1.z, f1.w);
    *(uint4*)((char*)dst + (size_t)(p * 32 + kt) * 8192 + phys_off(r, sl)) = u;
}

// ===========================================================================
// K2 FAST: pipelined pure-DMA fp16 MFMA GEMM, 128x256 block, 4 waves,
// per-wave tile 128x64 (halves LDS-read bytes per output vs 64x64).
// Triple-buffered, DMA 2 tiles ahead, counted vmcnt(6) (never 0 in loop).
// ===========================================================================
#define SBP   8192            // A image size
#define PBUF  24576           // 8 KB A + 16 KB B

__global__ __launch_bounds__(256, 2)
void k_score_pipe2(const unsigned short* __restrict__ Xsw,  // [256][32] 8KB imgs
                   const unsigned short* __restrict__ Wsw,  // [8][32] 8KB imgs
                   const float* __restrict__ hp,            // [16][1024]
                   const float* __restrict__ v,             // [1024]
                   float* __restrict__ score_part) {        // [32768][4]
    __shared__ char lds[3 * PBUF];   // 72 KB

    const int t = threadIdx.x;
    int wg = (blockIdx.x & 7) * 128 + (blockIdx.x >> 3);  // 1024 wgs, XCD-chunked
    const int mp  = wg >> 2;
    const int m0  = mp * 128;
    const int ntq = wg & 3;
    const int n0  = ntq * 256;

    const int lane = t & 63, wid = t >> 6;   // wave owns cols [wid*64, wid*64+64)
    const int lr = lane & 15, lq = lane >> 4;

    // DMA sources: wave wid covers A bytes [wid*2048,+2048), B bytes [wid*4096,+4096)
    const char* At = (const char*)Xsw + (size_t)mp * 32 * 8192 + wid * 2048 + lane * 16;
    const char* Bt = (const char*)Wsw + (size_t)((ntq * 2 + (wid >> 1)) * 32) * 8192
                     + (wid & 1) * 4096 + lane * 16;

    // fragment read offsets
    int aro[8], bro[4];
    #pragma unroll
    for (int i = 0; i < 8; ++i) aro[i] = phys_off(i * 16 + lr, lq);
    const int bbase = SBP + (wid >> 1) * 8192;
    #pragma unroll
    for (int j = 0; j < 4; ++j) bro[j] = bbase + phys_off((wid * 64 + j * 16 + lr) & 127, lq);

    f32x4 acc[8][4];
    #pragma unroll
    for (int i = 0; i < 8; ++i)
        #pragma unroll
        for (int j = 0; j < 4; ++j) acc[i][j] = (f32x4)0.f;

#define DMA2(bufbase, kt)                                                      \
    {                                                                          \
        const char* a = At + (size_t)(kt) * 8192;                              \
        const char* b = Bt + (size_t)(kt) * 8192;                              \
        dma16(a,        (bufbase) + wid * 2048);                               \
        dma16(a + 1024, (bufbase) + wid * 2048 + 1024);                        \
        dma16(b,        (bufbase) + SBP + wid * 4096);                         \
        dma16(b + 1024, (bufbase) + SBP + wid * 4096 + 1024);                  \
        dma16(b + 2048, (bufbase) + SBP + wid * 4096 + 2048);                  \
        dma16(b + 3072, (bufbase) + SBP + wid * 4096 + 3072);                  \
    }

    char* cb0 = lds;
    char* cb1 = lds + PBUF;
    char* cb2 = lds + 2 * PBUF;
    DMA2(cb0, 0);
    DMA2(cb1, 1);

    for (int kt = 0; kt < 32; ++kt) {
        if (kt < 31) { asm volatile("s_waitcnt vmcnt(6)" ::: "memory"); }
        else         { asm volatile("s_waitcnt vmcnt(0)" ::: "memory"); }
        __builtin_amdgcn_s_barrier();
        __builtin_amdgcn_sched_barrier(0);
        if (kt < 30) DMA2(cb2, kt + 2);

        half8 ah[8], bh[4];
        #pragma unroll
        for (int i = 0; i < 8; ++i) ah[i] = *(const half8*)(cb0 + aro[i]);
        #pragma unroll
        for (int j = 0; j < 4; ++j) bh[j] = *(const half8*)(cb0 + bro[j]);

        __builtin_amdgcn_s_setprio(1);
        #pragma unroll
        for (int i = 0; i < 8; ++i)
            #pragma unroll
            for (int j = 0; j < 4; ++j)
                acc[i][j] = __builtin_amdgcn_mfma_f32_16x16x32_f16(ah[i], bh[j], acc[i][j], 0, 0, 0);
        __builtin_amdgcn_s_setprio(0);

        char* tmp = cb0; cb0 = cb1; cb1 = cb2; cb2 = tmp;
    }
    __syncthreads();   // all tile reads done before red overlay

    // epilogue: D[row = i*16+lq*4+r][col = wid*64+j*16+lr]
    float* red = (float*)lds;          // [4][128]
    #pragma unroll
    for (int i = 0; i < 8; ++i) {
        #pragma unroll
        for (int r = 0; r < 4; ++r) {
            const int b = lq * 4 + r;  // global row & 15
            float s = 0.f;
            #pragma unroll
            for (int j = 0; j < 4; ++j) {
                const int c = n0 + wid * 64 + j * 16 + lr;
                s += v[c] * tanh_fast(acc[i][j][r] + hp[b * H_SZ + c]);
            }
            s += __shfl_xor(s, 1);
            s += __shfl_xor(s, 2);
            s += __shfl_xor(s, 4);
            s += __shfl_xor(s, 8);
            if (lr == 0)
                red[wid * 128 + i * 16 + lq * 4 + r] = s;
        }
    }
    __syncthreads();
    if (t < 128)
        score_part[(size_t)(m0 + t) * 4 + ntq] =
            red[t] + red[128 + t] + red[256 + t] + red[384 + t];
#undef DMA2
}

// ===========================================================================
// K2 FALLBACK (R10-proven): A reg-staged f32->f16, B DMA; writes [m][8]
// ===========================================================================
#define SA2   0
#define SB2   8192
#define SBUF2 16384

__global__ __launch_bounds__(256, 3)
void k_score_dma(const float* __restrict__ X,
                 const unsigned short* __restrict__ Wsw,
                 const float* __restrict__ hp,
                 const float* __restrict__ v,
                 float* __restrict__ score_part) {
    __shared__ char lds[2 * SBUF2];

    const int t = threadIdx.x;
    int wg = (blockIdx.x & 7) * 256 + (blockIdx.x >> 3);
    const int m0 = (wg >> 3) * 128;
    const int nt = wg & 7;
    const int n0 = nt * 128;

    const int lane = t & 63, wid = t >> 6;
    const int wm = wid >> 1, wn = wid & 1;
    const int lr = lane & 15, lq = lane >> 4;

    const int srow = t >> 1, shalf = t & 1;
    const float* Xp = X + (size_t)(m0 + srow) * 1024 + shalf * 16;
    const int aOff0 = phys_off(srow, shalf * 2 + 0);
    const int aOff1 = phys_off(srow, shalf * 2 + 1);

    const unsigned short* Bp = Wsw + (size_t)(nt * 32) * 4096 + wid * 512 + lane * 8;

    int aro[4], bro[4];
    #pragma unroll
    for (int i = 0; i < 4; ++i) {
        aro[i] = phys_off(wm * 64 + i * 16 + lr, lq);
        bro[i] = phys_off(wn * 64 + i * 16 + lr, lq);
    }

    f32x4 acc[4][4];
    #pragma unroll
    for (int i = 0; i < 4; ++i)
        #pragma unroll
        for (int j = 0; j < 4; ++j) acc[i][j] = (f32x4)0.f;

    float4 ax[4];

#define LOADA(kt)                                                              \
    {                                                                          \
        const float* p = Xp + (kt) * 32;                                       \
        ax[0] = *(const float4*)(p);                                           \
        ax[1] = *(const float4*)(p + 4);                                       \
        ax[2] = *(const float4*)(p + 8);                                       \
        ax[3] = *(const float4*)(p + 12);                                      \
    }

#define DMAB(bufbase, kt)                                                      \
    {                                                                          \
        const unsigned short* s0 = Bp + (size_t)(kt) * 4096;                   \
        dma16(s0,        (bufbase) + SB2 + wid * 1024);                        \
        dma16(s0 + 2048, (bufbase) + SB2 + wid * 1024 + 4096);                 \
    }

#define STAGEA(bufbase)                                                        \
    {                                                                          \
        uint4 p0, p1;                                                          \
        p0.x = pack2h(ax[0].x, ax[0].y); p0.y = pack2h(ax[0].z, ax[0].w);      \
        p0.z = pack2h(ax[1].x, ax[1].y); p0.w = pack2h(ax[1].z, ax[1].w);      \
        p1.x = pack2h(ax[2].x, ax[2].y); p1.y = pack2h(ax[2].z, ax[2].w);      \
        p1.z = pack2h(ax[3].x, ax[3].y); p1.w = pack2h(ax[3].z, ax[3].w);      \
        *(uint4*)((bufbase) + SA2 + aOff0) = p0;                               \
        *(uint4*)((bufbase) + SA2 + aOff1) = p1;                               \
    }

    LOADA(0);
    DMAB(lds, 0);
    STAGEA(lds);
    __syncthreads();

    for (int kt = 0; kt < 32; ++kt) {
        char* cur = lds + (kt & 1) * SBUF2;
        char* nxt = lds + ((kt & 1) ^ 1) * SBUF2;
        if (kt < 31) {
            LOADA(kt + 1);
            DMAB(nxt, kt + 1);
        }

        half8 ah[4], bh[4];
        #pragma unroll
        for (int i = 0; i < 4; ++i) ah[i] = *(const half8*)(cur + SA2 + aro[i]);
        #pragma unroll
        for (int j = 0; j < 4; ++j) bh[j] = *(const half8*)(cur + SB2 + bro[j]);

        #pragma unroll
        for (int i = 0; i < 4; ++i)
            #pragma unroll
            for (int j = 0; j < 4; ++j)
                acc[i][j] = __builtin_amdgcn_mfma_f32_16x16x32_f16(ah[i], bh[j], acc[i][j], 0, 0, 0);

        if (kt < 31) STAGEA(nxt);
        __syncthreads();
    }

    float* red = (float*)lds;
    #pragma unroll
    for (int i = 0; i < 4; ++i) {
        #pragma unroll
        for (int r = 0; r < 4; ++r) {
            const int b = lq * 4 + r;
            float s = 0.f;
            #pragma unroll
            for (int j = 0; j < 4; ++j) {
                const int c = n0 + wn * 64 + j * 16 + lr;
                s += v[c] * tanh_fast(acc[i][j][r] + hp[b * H_SZ + c]);
            }
            s += __shfl_xor(s, 1);
            s += __shfl_xor(s, 2);
            s += __shfl_xor(s, 4);
            s += __shfl_xor(s, 8);
            if (lr == 0)
                red[wn * 128 + wm * 64 + i * 16 + lq * 4 + r] = s;
        }
    }
    __syncthreads();
    if (t < 128)
        score_part[(size_t)(m0 + t) * 8 + nt] = red[t] + red[128 + t];
#undef LOADA
#undef DMAB
#undef STAGEA
}

// ---------------------------------------------------------------------------
// K3: fold contiguous partials per (s,b), mask, softmax over b -> wts.
// ---------------------------------------------------------------------------
__global__ void k_softmax4(const float* __restrict__ sp,   // [m][4]
                           const int* __restrict__ masks,
                           float* __restrict__ wts) {
    int s = blockIdx.x * blockDim.x + threadIdx.x;
    if (s >= S_LEN) return;
    const float4* base = (const float4*)(sp + (size_t)s * 64);
    float vals[16];
    float mx = -INFINITY;
    #pragma unroll
    for (int b = 0; b < 16; ++b) {
        float4 p = base[b];
        float sc = (p.x + p.y) + (p.z + p.w);
        sc = masks[s * 16 + b] ? sc : -1e10f;
        vals[b] = sc;
        mx = fmaxf(mx, sc);
    }
    float sum = 0.f;
    #pragma unroll
    for (int b = 0; b < 16; ++b) { vals[b] = __expf(vals[b] - mx); sum += vals[b]; }
    float inv = 1.f / sum;
    #pragma unroll
    for (int b = 0; b < 16; ++b) wts[s * 16 + b] = vals[b] * inv;
}

__global__ void k_softmax8(const float* __restrict__ sp,   // [m][8]
                           const int* __restrict__ masks,
                           float* __restrict__ wts) {
    int s = blockIdx.x * blockDim.x + threadIdx.x;
    if (s >= S_LEN) return;
    const float4* base = (const float4*)(sp + (size_t)s * 128);
    float vals[16];
    float mx = -INFINITY;
    #pragma unroll
    for (int b = 0; b < 16; ++b) {
        float4 p0 = base[b * 2], p1 = base[b * 2 + 1];
        float sc = ((p0.x + p0.y) + (p0.z + p0.w)) + ((p1.x + p1.y) + (p1.z + p1.w));
        sc = masks[s * 16 + b] ? sc : -1e10f;
        vals[b] = sc;
        mx = fmaxf(mx, sc);
    }
    float sum = 0.f;
    #pragma unroll
    for (int b = 0; b < 16; ++b) { vals[b] = __expf(vals[b] - mx); sum += vals[b]; }
    float inv = 1.f / sum;
    #pragma unroll
    for (int b = 0; b < 16; ++b) wts[s * 16 + b] = vals[b] * inv;
}

// ---------------------------------------------------------------------------
// K4a: context partials from f16 Xsw (R10-proven). Block (c,b), 64 s-steps.
// ---------------------------------------------------------------------------
__global__ __launch_bounds__(256)
void k_context_f16(const float* __restrict__ wts,
                   const unsigned short* __restrict__ Xsw,
                   float* __restrict__ partial) {     // [32][16][1024]
    const int t = threadIdx.x;
    const int b = blockIdx.x & 15;
    const int c = blockIdx.x >> 4;
    const int kt = t >> 3;
    const int sl = (t >> 1) & 3;
    const int e8 = (t & 1) * 8;

    int po[8];
    #pragma unroll
    for (int j = 0; j < 8; ++j) po[j] = phys_off(b + j * 16, sl) + e8;

    const char* base = (const char*)Xsw + ((size_t)(c * 8) * 32 + kt) * 8192;
    float4 acc = make_float4(0.f, 0.f, 0.f, 0.f);
    #pragma unroll
    for (int o = 0; o < 8; ++o) {
        const char* tb = base + (size_t)o * 32 * 8192;
        #pragma unroll
        for (int j = 0; j < 8; ++j) {
            const int s = c * 64 + o * 8 + j;
            float w = wts[s * 16 + b];
            half4 x = *(const half4*)(tb + po[j]);
            acc.x += w * (float)x[0];
            acc.y += w * (float)x[1];
            acc.z += w * (float)x[2];
            acc.w += w * (float)x[3];
        }
    }
    *(float4*)(partial + (size_t)(c * 16 + b) * 1024 + t * 4) = acc;
}

// K4a FALLBACK: f32 X, 32 chunks of 64 s.
__global__ void k_context_partial(const float* __restrict__ wts,
                                  const float* __restrict__ X,
                                  float* __restrict__ partial) {
    int b = blockIdx.x & 15;
    int c = blockIdx.x >> 4;
    int h = threadIdx.x * 4;
    float4 acc = make_float4(0.f, 0.f, 0.f, 0.f);
    for (int s = c * 64; s < c * 64 + 64; ++s) {
        float w = wts[s * 16 + b];
        float4 x = *(const float4*)(X + (size_t)(s * 16 + b) * 1024 + h);
        acc.x += w * x.x; acc.y += w * x.y; acc.z += w * x.z; acc.w += w * x.w;
    }
    *(float4*)(partial + (size_t)(c * 16 + b) * 1024 + h) = acc;
}

__global__ void k_context_reduce(const float* __restrict__ partial,
                                 float* __restrict__ out) {
    int o = blockIdx.x * blockDim.x + threadIdx.x;  // 16384
    int b = o >> 10, h = o & 1023;
    float s = 0.f;
    #pragma unroll
    for (int cc = 0; cc < 32; ++cc) s += partial[(size_t)(cc * 16 + b) * 1024 + h];
    out[o] = s;
}

extern "C" void kernel_launch(void* const* d_in, const int* in_sizes, int n_in,
                              void* d_out, int out_size, void* d_ws, size_t ws_size,
                              hipStream_t stream) {
    const float* hidden = (const float*)d_in[0];
    const float* hseq   = (const float*)d_in[1];
    const int*   masks  = (const int*)d_in[2];
    const float* W      = (const float*)d_in[3];
    const float* b_att  = (const float*)d_in[4];
    const float* v      = (const float*)d_in[5];
    float* out = (float*)d_out;

    // ws layout (float units):
    //   hp[16384] | wts[32768] | score_part[32768*8] | partial[32*16*1024]
    //   | Wsw[2MB] | Xsw[64MB]
    float* wsf        = (float*)d_ws;
    float* hp         = wsf;
    float* wts        = wsf + 16384;
    float* score_part = wts + 32768;
    float* partial    = score_part + 8 * M_SZ;
    unsigned short* Wsw = (unsigned short*)(partial + 32 * 16 * 1024);
    unsigned short* Xsw = (unsigned short*)((char*)Wsw + 2 * 1024 * 1024);
    const size_t WS_FAST = (size_t)(16384 + 32768 + 262144 + 524288) * 4
                         + 2ull * 1024 * 1024 + 64ull * 1024 * 1024;

    hipLaunchKernelGGL(k_hidden_conv, dim3(4096), dim3(256), 0, stream, hidden, W, b_att, hp, Wsw);
    if (ws_size >= WS_FAST) {
        hipLaunchKernelGGL(k_conv_tiles,   dim3(16384), dim3(256), 0, stream, hseq, Xsw, 1024, 0);
        hipLaunchKernelGGL(k_score_pipe2,  dim3(1024),  dim3(256), 0, stream, Xsw, Wsw, hp, v, score_part);
        hipLaunchKernelGGL(k_softmax4,     dim3(8),     dim3(256), 0, stream, score_part, masks, wts);
        hipLaunchKernelGGL(k_context_f16,  dim3(512),   dim3(256), 0, stream, wts, Xsw, partial);
    } else {
        hipLaunchKernelGGL(k_score_dma,    dim3(2048),  dim3(256), 0, stream, hseq, Wsw, hp, v, score_part);
        hipLaunchKernelGGL(k_softmax8,     dim3(8),     dim3(256), 0, stream, score_part, masks, wts);
        hipLaunchKernelGGL(k_context_partial, dim3(512), dim3(256), 0, stream, wts, hseq, partial);
    }
    hipLaunchKernelGGL(k_context_reduce, dim3(64), dim3(256), 0, stream, partial, out);
}